// Round 1
// baseline (1294.279 us; speedup 1.0000x reference)
//
#include <hip/hip_runtime.h>
#include <math.h>

// FastGTNLayer: out = (sum_e scale[e]*A[e]) @ X @ lin_w^T + lin_b + bias
//   scale[e] = sum_c softmax(weight, axis=0)[e,c]
// A: [4][8192][8192] f32 (1.07 GB, streamed once -> memory bound, floor ~170us)
// Strategy: fp32 VALU GEMM (no fp32 MFMA on CDNA4), LDS-tiled, reg double-buffered.

#define NN_      8192
#define CH_      64
#define MB_      64          // rows per block
#define KT_      32          // k-tile
#define KSPLIT_  4           // k-split across blocks (atomics into out)
#define AGS_     68          // aggT row stride (floats): %4==0 for b128 align, banks ok
#define NKT_     ((NN_ / KSPLIT_) / KT_)   // 64 tiles per block

__global__ void gtn_zero(float4* __restrict__ out4) {
  out4[(size_t)blockIdx.x * 256 + threadIdx.x] = make_float4(0.f, 0.f, 0.f, 0.f);
}

__global__ __launch_bounds__(256, 2)
void gtn_main(const float* __restrict__ A, const float* __restrict__ X,
              const float* __restrict__ Wt, float* __restrict__ out) {
  __shared__ __align__(16) float aggT[2][KT_][AGS_];  // [kk][row], padded stride
  __shared__ __align__(16) float yT[2][KT_][CH_];     // [kk][ch]

  const int tid = threadIdx.x;
  const int mt  = blockIdx.x >> 2;      // 0..127  (row tile)
  const int ks  = blockIdx.x & 3;       // 0..3    (k split)
  const int n0  = mt * MB_;
  const int k0  = ks * (NN_ / KSPLIT_);

  // per-thread recompute of scale[e] (8 loads + ~30 ops, negligible)
  float sc0, sc1, sc2, sc3;
  {
    float a0 = Wt[0], a1 = Wt[2], a2 = Wt[4], a3 = Wt[6];   // channel 0
    float b0 = Wt[1], b1 = Wt[3], b2 = Wt[5], b3 = Wt[7];   // channel 1
    float ma = fmaxf(fmaxf(a0, a1), fmaxf(a2, a3));
    float mb = fmaxf(fmaxf(b0, b1), fmaxf(b2, b3));
    float ea0 = expf(a0 - ma), ea1 = expf(a1 - ma), ea2 = expf(a2 - ma), ea3 = expf(a3 - ma);
    float eb0 = expf(b0 - mb), eb1 = expf(b1 - mb), eb2 = expf(b2 - mb), eb3 = expf(b3 - mb);
    float ra = 1.f / (ea0 + ea1 + ea2 + ea3);
    float rb = 1.f / (eb0 + eb1 + eb2 + eb3);
    sc0 = ea0 * ra + eb0 * rb;  sc1 = ea1 * ra + eb1 * rb;
    sc2 = ea2 * ra + eb2 * rb;  sc3 = ea3 * ra + eb3 * rb;
  }

  // inner-GEMM thread tile: 4 rows x 4 channels
  const int rg = tid & 15;        // row group   (16 x 4 = 64 rows)
  const int cg = tid >> 4;        // chan group  (16 x 4 = 64 ch)

  // staging maps
  const int kkq = tid & 7;        // A: k-quad 0..7 (covers KT=32)
  const int sr0 = tid >> 3;       // A: row 0..31 (+32 for slot 1)
  const int ycq = tid & 15;       // X: ch-quad 0..15
  const int yk0 = tid >> 4;       // X: kk 0..15 (+16 for slot 1)

  const size_t NNsq = (size_t)NN_ * NN_;
  const float* aP[2][4];
#pragma unroll
  for (int s = 0; s < 2; ++s) {
    const int r = sr0 + 32 * s;
#pragma unroll
    for (int e = 0; e < 4; ++e)
      aP[s][e] = A + (size_t)e * NNsq + (size_t)(n0 + r) * NN_ + (k0 + kkq * 4);
  }
  const float* xP[2];
#pragma unroll
  for (int s = 0; s < 2; ++s)
    xP[s] = X + (size_t)(k0 + yk0 + 16 * s) * CH_ + ycq * 4;

  float acc[4][4];
#pragma unroll
  for (int i = 0; i < 4; ++i)
#pragma unroll
    for (int j = 0; j < 4; ++j) acc[i][j] = 0.f;

  float4 la[2][4], ly[2];

  // ---- prologue: load + stage tile 0 into buf 0
#pragma unroll
  for (int s = 0; s < 2; ++s) {
#pragma unroll
    for (int e = 0; e < 4; ++e) la[s][e] = *(const float4*)(aP[s][e]);
    ly[s] = *(const float4*)(xP[s]);
  }
#pragma unroll
  for (int s = 0; s < 2; ++s) {
    float4 g;
    g.x = sc0 * la[s][0].x + sc1 * la[s][1].x + sc2 * la[s][2].x + sc3 * la[s][3].x;
    g.y = sc0 * la[s][0].y + sc1 * la[s][1].y + sc2 * la[s][2].y + sc3 * la[s][3].y;
    g.z = sc0 * la[s][0].z + sc1 * la[s][1].z + sc2 * la[s][2].z + sc3 * la[s][3].z;
    g.w = sc0 * la[s][0].w + sc1 * la[s][1].w + sc2 * la[s][2].w + sc3 * la[s][3].w;
    const int r = sr0 + 32 * s;
    aggT[0][kkq * 4 + 0][r] = g.x;
    aggT[0][kkq * 4 + 1][r] = g.y;
    aggT[0][kkq * 4 + 2][r] = g.z;
    aggT[0][kkq * 4 + 3][r] = g.w;
    *(float4*)&yT[0][yk0 + 16 * s][ycq * 4] = ly[s];
  }
  __syncthreads();

  // ---- main loop: reg-staged double buffer
  for (int kt = 0; kt < NKT_; ++kt) {
    const int b = kt & 1;
    const bool more = (kt + 1 < NKT_);

    if (more) {  // issue next-tile global loads (latency hides under compute)
#pragma unroll
      for (int s = 0; s < 2; ++s) {
#pragma unroll
        for (int e = 0; e < 4; ++e)
          la[s][e] = *(const float4*)(aP[s][e] + (size_t)(kt + 1) * KT_);
        ly[s] = *(const float4*)(xP[s] + (size_t)(kt + 1) * KT_ * CH_);
      }
    }

    // compute current buffer: 32 k-steps x 16 FMA
#pragma unroll
    for (int kk = 0; kk < KT_; ++kk) {
      float4 ag = *(const float4*)&aggT[b][kk][rg * 4];
      float4 yv = *(const float4*)&yT[b][kk][cg * 4];
      float av[4] = {ag.x, ag.y, ag.z, ag.w};
      float yw[4] = {yv.x, yv.y, yv.z, yv.w};
#pragma unroll
      for (int i = 0; i < 4; ++i)
#pragma unroll
        for (int j = 0; j < 4; ++j)
          acc[i][j] = fmaf(av[i], yw[j], acc[i][j]);
    }

    if (more) {  // combine edges + write next buffer
#pragma unroll
      for (int s = 0; s < 2; ++s) {
        float4 g;
        g.x = sc0 * la[s][0].x + sc1 * la[s][1].x + sc2 * la[s][2].x + sc3 * la[s][3].x;
        g.y = sc0 * la[s][0].y + sc1 * la[s][1].y + sc2 * la[s][2].y + sc3 * la[s][3].y;
        g.z = sc0 * la[s][0].z + sc1 * la[s][1].z + sc2 * la[s][2].z + sc3 * la[s][3].z;
        g.w = sc0 * la[s][0].w + sc1 * la[s][1].w + sc2 * la[s][2].w + sc3 * la[s][3].w;
        const int r = sr0 + 32 * s;
        aggT[b ^ 1][kkq * 4 + 0][r] = g.x;
        aggT[b ^ 1][kkq * 4 + 1][r] = g.y;
        aggT[b ^ 1][kkq * 4 + 2][r] = g.z;
        aggT[b ^ 1][kkq * 4 + 3][r] = g.w;
        *(float4*)&yT[b ^ 1][yk0 + 16 * s][ycq * 4] = ly[s];
      }
    }
    __syncthreads();
  }

  // ---- epilogue: accumulate partial H = Aagg @ X into out (zeroed before)
#pragma unroll
  for (int i = 0; i < 4; ++i)
#pragma unroll
    for (int j = 0; j < 4; ++j)
      atomicAdd(&out[(size_t)(n0 + rg * 4 + i) * CH_ + (cg * 4 + j)], acc[i][j]);
}

// in-place: out_row = H_row @ lin_w^T + lin_b + bias
__global__ __launch_bounds__(64)
void gtn_finalize(float* __restrict__ out, const float* __restrict__ lw,
                  const float* __restrict__ lb, const float* __restrict__ bias) {
  __shared__ float h[CH_];
  const int row = blockIdx.x, c = threadIdx.x;
  h[c] = out[(size_t)row * CH_ + c];
  __syncthreads();
  float a = lb[c] + bias[c];
#pragma unroll
  for (int k = 0; k < CH_; ++k) a = fmaf(h[k], lw[c * CH_ + k], a);
  out[(size_t)row * CH_ + c] = a;
}

extern "C" void kernel_launch(void* const* d_in, const int* in_sizes, int n_in,
                              void* d_out, int out_size, void* d_ws, size_t ws_size,
                              hipStream_t stream) {
  const float* A    = (const float*)d_in[0];
  const float* X    = (const float*)d_in[1];
  const float* Wt   = (const float*)d_in[2];
  const float* lw   = (const float*)d_in[3];
  const float* lb   = (const float*)d_in[4];
  const float* bias = (const float*)d_in[5];
  float* out = (float*)d_out;

  gtn_zero<<<dim3(out_size / 1024), 256, 0, stream>>>((float4*)out);           // 512 blocks
  gtn_main<<<dim3((NN_ / MB_) * KSPLIT_), 256, 0, stream>>>(A, X, Wt, out);    // 512 blocks
  gtn_finalize<<<dim3(NN_), 64, 0, stream>>>(out, lw, lb, bias);
}

// Round 2
// 341.778 us; speedup vs baseline: 3.7869x; 3.7869x over previous
//
#include <hip/hip_runtime.h>
#include <math.h>

// FastGTNLayer fused: out = (sum_e scale[e]*A[e]) @ X @ lin_w^T + lin_b + bias
// A: [4][8192][8192] f32, streamed exactly once via global_load_lds DMA.
// 512 blocks x 256 thr; block owns 16 rows, full K; no atomics, no scratch state.

#define NN 8192
#define CH 64
#define RB 16                 // rows per block
#define KT 64                 // k-tile
#define NT (NN / KT)          // 128 tiles
#define NBLK (NN / RB)        // 512 blocks

#define A_BUF_F 4096          // floats per A buffer: 4e * 16r * 64k
#define X_BUF_F 4096          // floats per X buffer: 64k * 64ch
#define OFF_A0 0
#define OFF_A1 (A_BUF_F)
#define OFF_X0 (2 * A_BUF_F)
#define OFF_X1 (2 * A_BUF_F + X_BUF_F)
#define AGG_STRIDE 68
#define AGG_BUF_F (RB * AGG_STRIDE)
#define OFF_AGG0 (2 * A_BUF_F + 2 * X_BUF_F)
#define OFF_AGG1 (OFF_AGG0 + AGG_BUF_F)
#define LDS_FLOATS (OFF_AGG1 + AGG_BUF_F)   // 18560 floats = 74.24 KB -> 2 blocks/CU

__device__ __forceinline__ void dma16(const float* g, float* l) {
  __builtin_amdgcn_global_load_lds(
      (const __attribute__((address_space(1))) void*)g,
      (__attribute__((address_space(3))) void*)l, 16, 0, 0);
}

__global__ __launch_bounds__(256)
void gtn_fused(const float* __restrict__ A, const float* __restrict__ X,
               const float* __restrict__ Wt, const float* __restrict__ lw,
               const float* __restrict__ lb, const float* __restrict__ bias,
               float* __restrict__ out) {
  __shared__ __align__(16) float arena[LDS_FLOATS];

  const int tid = threadIdx.x;
  const int n0  = blockIdx.x * RB;

  // scale[e] = sum_c softmax(weight, axis=0)[e,c]   (8 scalar loads, cached)
  float sc0, sc1, sc2, sc3;
  {
    float a0 = Wt[0], a1 = Wt[2], a2 = Wt[4], a3 = Wt[6];
    float b0 = Wt[1], b1 = Wt[3], b2 = Wt[5], b3 = Wt[7];
    float ma = fmaxf(fmaxf(a0, a1), fmaxf(a2, a3));
    float mb = fmaxf(fmaxf(b0, b1), fmaxf(b2, b3));
    float ea0 = expf(a0 - ma), ea1 = expf(a1 - ma), ea2 = expf(a2 - ma), ea3 = expf(a3 - ma);
    float eb0 = expf(b0 - mb), eb1 = expf(b1 - mb), eb2 = expf(b2 - mb), eb3 = expf(b3 - mb);
    float ra = 1.f / (ea0 + ea1 + ea2 + ea3);
    float rb = 1.f / (eb0 + eb1 + eb2 + eb3);
    sc0 = ea0 * ra + eb0 * rb;  sc1 = ea1 * ra + eb1 * rb;
    sc2 = ea2 * ra + eb2 * rb;  sc3 = ea3 * ra + eb3 * rb;
  }

  // ---- DMA source base pointers (k = 0), granule s = tid + i*256, 16 B each
  // A granule s: e = s>>8, r = (s>>4)&15, kq = s&15  -> LDS [e][r][kq*4], linear.
  const float* gA[4];
  const float* gX[4];
#pragma unroll
  for (int i = 0; i < 4; ++i) {
    const int s = tid + i * 256;
    const int e = s >> 8, r = (s >> 4) & 15, kq = s & 15;
    gA[i] = A + ((size_t)e << 26) + (size_t)(n0 + r) * NN + kq * 4;
    const int kk = s >> 4, cq = s & 15;           // X granule: [kk][cq*4]
    gX[i] = X + (size_t)kk * CH + cq * 4;
  }

  const int rg = tid >> 4;     // 0..15 : row      (GEMM/combine/finalize)
  const int cg = tid & 15;     // 0..15 : ch-quad / k-quad

  // ---- prologue: DMA tile 0 into buffer 0
#pragma unroll
  for (int i = 0; i < 4; ++i) dma16(gA[i], &arena[OFF_A0 + (tid + i * 256) * 4]);
#pragma unroll
  for (int i = 0; i < 4; ++i) dma16(gX[i], &arena[OFF_X0 + (tid + i * 256) * 4]);

  float4 acc = make_float4(0.f, 0.f, 0.f, 0.f);

  for (int t = 0; t < NT; ++t) {
    const int b = t & 1;

    // #A: tile-t DMA landed (mine via vmcnt, all waves via barrier);
    //     all waves done with GEMM(t-1) -> buf[b^1] free for DMA(t+1).
    asm volatile("s_waitcnt vmcnt(0)\n\ts_barrier" ::: "memory");

    if (t + 1 < NT) {   // issue next tile's DMA; lands any time before next #A
      const size_t koff = (size_t)(t + 1) * KT;
      float* Ad = &arena[b ? OFF_A0 : OFF_A1];
      float* Xd = &arena[b ? OFF_X0 : OFF_X1];
#pragma unroll
      for (int i = 0; i < 4; ++i) dma16(gA[i] + koff, Ad + (tid + i * 256) * 4);
#pragma unroll
      for (int i = 0; i < 4; ++i) dma16(gX[i] + koff * CH, Xd + (tid + i * 256) * 4);
    }

    // ---- combine: agg[r][k] = sum_e sc[e] * A_e[r][k]   (thread: r=rg, kq=cg)
    {
      const float* Ab = &arena[b ? OFF_A1 : OFF_A0];
      float* aggW = &arena[b ? OFF_AGG1 : OFF_AGG0];
      float4 g = make_float4(0.f, 0.f, 0.f, 0.f);
#pragma unroll
      for (int e = 0; e < 4; ++e) {
        const float s = (e == 0) ? sc0 : (e == 1) ? sc1 : (e == 2) ? sc2 : sc3;
        float4 v = *(const float4*)&Ab[(e * RB + rg) * KT + cg * 4];
        g.x = fmaf(s, v.x, g.x); g.y = fmaf(s, v.y, g.y);
        g.z = fmaf(s, v.z, g.z); g.w = fmaf(s, v.w, g.w);
      }
      *(float4*)&aggW[rg * AGG_STRIDE + cg * 4] = g;
    }

    // #B: agg writes visible to all waves
    asm volatile("s_waitcnt lgkmcnt(0)\n\ts_barrier" ::: "memory");

    // ---- GEMM: acc[rg][cg*4..+4) += agg[rg][k] * X[k][cg*4..+4)
    {
      const float* aggB = &arena[b ? OFF_AGG1 : OFF_AGG0];
      const float* xB   = &arena[b ? OFF_X1  : OFF_X0];
#pragma unroll
      for (int k4 = 0; k4 < KT / 4; ++k4) {
        float4 a4 = *(const float4*)&aggB[rg * AGG_STRIDE + k4 * 4];
#pragma unroll
        for (int jj = 0; jj < 4; ++jj) {
          const float a = (jj == 0) ? a4.x : (jj == 1) ? a4.y : (jj == 2) ? a4.z : a4.w;
          float4 xv = *(const float4*)&xB[(k4 * 4 + jj) * CH + cg * 4];
          acc.x = fmaf(a, xv.x, acc.x);
          acc.y = fmaf(a, xv.y, acc.y);
          acc.z = fmaf(a, xv.z, acc.z);
          acc.w = fmaf(a, xv.w, acc.w);
        }
      }
    }
  }

  // ---- finalize in-block: out_row = H_row @ lin_w^T + lin_b + bias
  __syncthreads();                       // loop fully done; safe full drain
  float* hT = arena;                     // reuse: 16 x 68
  *(float4*)&hT[rg * AGG_STRIDE + cg * 4] = acc;
  __syncthreads();

  const int c0 = cg * 4;
  float s0 = lb[c0 + 0] + bias[c0 + 0];
  float s1 = lb[c0 + 1] + bias[c0 + 1];
  float s2 = lb[c0 + 2] + bias[c0 + 2];
  float s3 = lb[c0 + 3] + bias[c0 + 3];
#pragma unroll
  for (int k4 = 0; k4 < CH / 4; ++k4) {
    float4 hv = *(const float4*)&hT[rg * AGG_STRIDE + k4 * 4];
    float4 w0 = *(const float4*)&lw[(size_t)(c0 + 0) * CH + k4 * 4];
    float4 w1 = *(const float4*)&lw[(size_t)(c0 + 1) * CH + k4 * 4];
    float4 w2 = *(const float4*)&lw[(size_t)(c0 + 2) * CH + k4 * 4];
    float4 w3 = *(const float4*)&lw[(size_t)(c0 + 3) * CH + k4 * 4];
    s0 += hv.x * w0.x + hv.y * w0.y + hv.z * w0.z + hv.w * w0.w;
    s1 += hv.x * w1.x + hv.y * w1.y + hv.z * w1.z + hv.w * w1.w;
    s2 += hv.x * w2.x + hv.y * w2.y + hv.z * w2.z + hv.w * w2.w;
    s3 += hv.x * w3.x + hv.y * w3.y + hv.z * w3.z + hv.w * w3.w;
  }
  *(float4*)&out[(size_t)(n0 + rg) * CH + c0] = make_float4(s0, s1, s2, s3);
}

extern "C" void kernel_launch(void* const* d_in, const int* in_sizes, int n_in,
                              void* d_out, int out_size, void* d_ws, size_t ws_size,
                              hipStream_t stream) {
  const float* A    = (const float*)d_in[0];
  const float* X    = (const float*)d_in[1];
  const float* Wt   = (const float*)d_in[2];
  const float* lw   = (const float*)d_in[3];
  const float* lb   = (const float*)d_in[4];
  const float* bias = (const float*)d_in[5];
  float* out = (float*)d_out;

  gtn_fused<<<dim3(NBLK), 256, 0, stream>>>(A, X, Wt, lw, lb, bias, out);
}

// Round 3
// 263.666 us; speedup vs baseline: 4.9088x; 1.2963x over previous
//
#include <hip/hip_runtime.h>
#include <math.h>

// FastGTNLayer fused: out = (sum_e scale[e]*A[e]) @ X @ lin_w^T + lin_b + bias
// A: [4][8192][8192] f32, streamed once via global_load_lds DMA (HBM floor ~170us).
// GEMM on matrix pipe: combine fp32 -> bf16 agg -> mfma_f32_16x16x32_bf16.

#define NN 8192
#define CH 64
#define RB 16                 // rows per block
#define KT 64                 // k-tile
#define NT (NN / KT)          // 128 tiles
#define NBLK (NN / RB)        // 512 blocks

#define A_BUF_F 4096          // 4e * 16r * 64k floats
#define X_BUF_F 4096          // 64k * 64ch floats
#define OFF_A0 0
#define OFF_A1 (A_BUF_F)
#define OFF_X0 (2 * A_BUF_F)
#define OFF_X1 (2 * A_BUF_F + X_BUF_F)
#define OFF_AGG (2 * A_BUF_F + 2 * X_BUF_F)   // shorts from here
#define AGG_STRIDE_S 72       // shorts per agg row: 144B = 16B-aligned, bank-free
#define AGG_F ((RB * AGG_STRIDE_S + 1) / 2)   // 576 floats
#define LDS_FLOATS (OFF_AGG + AGG_F)          // 16960 floats = 67.84 KB -> 2 blk/CU
#define HT_STRIDE 68

typedef __attribute__((ext_vector_type(8))) short bf16x8;
typedef __attribute__((ext_vector_type(4))) float f32x4;

__device__ __forceinline__ void dma16(const float* g, float* l) {
  __builtin_amdgcn_global_load_lds(
      (const __attribute__((address_space(1))) void*)g,
      (__attribute__((address_space(3))) void*)l, 16, 0, 0);
}

__device__ __forceinline__ unsigned f2bfu(float f) {   // fp32 -> bf16 bits, RNE
  unsigned u = __float_as_uint(f);
  return (u + 0x7FFFu + ((u >> 16) & 1u)) >> 16;
}

__global__ __launch_bounds__(256)
void gtn_fused(const float* __restrict__ A, const float* __restrict__ X,
               const float* __restrict__ Wt, const float* __restrict__ lw,
               const float* __restrict__ lb, const float* __restrict__ bias,
               float* __restrict__ out) {
  __shared__ __align__(16) float arena[LDS_FLOATS];

  const int tid = threadIdx.x;
  const int n0  = blockIdx.x * RB;

  // scale[e] = sum_c softmax(weight, axis=0)[e,c]
  float sc0, sc1, sc2, sc3;
  {
    float a0 = Wt[0], a1 = Wt[2], a2 = Wt[4], a3 = Wt[6];
    float b0 = Wt[1], b1 = Wt[3], b2 = Wt[5], b3 = Wt[7];
    float ma = fmaxf(fmaxf(a0, a1), fmaxf(a2, a3));
    float mb = fmaxf(fmaxf(b0, b1), fmaxf(b2, b3));
    float ea0 = expf(a0 - ma), ea1 = expf(a1 - ma), ea2 = expf(a2 - ma), ea3 = expf(a3 - ma);
    float eb0 = expf(b0 - mb), eb1 = expf(b1 - mb), eb2 = expf(b2 - mb), eb3 = expf(b3 - mb);
    float ra = 1.f / (ea0 + ea1 + ea2 + ea3);
    float rb = 1.f / (eb0 + eb1 + eb2 + eb3);
    sc0 = ea0 * ra + eb0 * rb;  sc1 = ea1 * ra + eb1 * rb;
    sc2 = ea2 * ra + eb2 * rb;  sc3 = ea3 * ra + eb3 * rb;
  }

  // DMA source bases (k=0); granule s = tid + i*256, 16 B each, LDS linear.
  const float* gA[4];
  const float* gX[4];
#pragma unroll
  for (int i = 0; i < 4; ++i) {
    const int s = tid + i * 256;
    const int e = s >> 8, r = (s >> 4) & 15, kq = s & 15;   // A: [e][r][kq*4]
    gA[i] = A + ((size_t)e << 26) + (size_t)(n0 + r) * NN + kq * 4;
    const int kk = s >> 4, cq = s & 15;                     // X: [kk][cq*4]
    gX[i] = X + (size_t)kk * CH + cq * 4;
  }

  const int rg = tid >> 4, cg = tid & 15;       // combine / finalize map
  const int lane = tid & 63, wv = tid >> 6;     // mfma map
  const int ch0 = wv * 16;
  const int fm = lane & 15, fg = lane >> 4;

  // prologue: DMA tile 0 into buffer 0
#pragma unroll
  for (int i = 0; i < 4; ++i) dma16(gA[i], &arena[OFF_A0 + (tid + i * 256) * 4]);
#pragma unroll
  for (int i = 0; i < 4; ++i) dma16(gX[i], &arena[OFF_X0 + (tid + i * 256) * 4]);

  f32x4 acc = {0.f, 0.f, 0.f, 0.f};

  for (int t = 0; t < NT; ++t) {
    const int b = t & 1;

    // #A: tile-t DMA landed; everyone done with mfma(t-1) -> agg free, buf b^1 free
    asm volatile("s_waitcnt vmcnt(0)\n\ts_barrier" ::: "memory");

    if (t + 1 < NT) {
      const size_t koff = (size_t)(t + 1) * KT;
      float* Ad = &arena[b ? OFF_A0 : OFF_A1];
      float* Xd = &arena[b ? OFF_X0 : OFF_X1];
#pragma unroll
      for (int i = 0; i < 4; ++i) dma16(gA[i] + koff, Ad + (tid + i * 256) * 4);
#pragma unroll
      for (int i = 0; i < 4; ++i) dma16(gX[i] + koff * CH, Xd + (tid + i * 256) * 4);
    }

    // combine: agg[k][r] -> bf16, stored m-major [16][72 shorts]
    {
      const float* Ab = &arena[b ? OFF_A1 : OFF_A0];
      short* aggW = (short*)&arena[OFF_AGG];
      float gx = 0.f, gy = 0.f, gz = 0.f, gw = 0.f;
#pragma unroll
      for (int e = 0; e < 4; ++e) {
        const float s = (e == 0) ? sc0 : (e == 1) ? sc1 : (e == 2) ? sc2 : sc3;
        float4 v = *(const float4*)&Ab[(e * RB + rg) * KT + cg * 4];
        gx = fmaf(s, v.x, gx); gy = fmaf(s, v.y, gy);
        gz = fmaf(s, v.z, gz); gw = fmaf(s, v.w, gw);
      }
      unsigned u0 = f2bfu(gx) | (f2bfu(gy) << 16);
      unsigned u1 = f2bfu(gz) | (f2bfu(gw) << 16);
      *(uint2*)&aggW[rg * AGG_STRIDE_S + cg * 4] = make_uint2(u0, u1);
    }

    // #B: agg visible to all waves
    asm volatile("s_waitcnt lgkmcnt(0)\n\ts_barrier" ::: "memory");

    // mfma: wave wv owns out[0:16][ch0:ch0+16]; 2 x (16x16x32) per tile
    {
      const short* aggS = (const short*)&arena[OFF_AGG];
      const float* Xb   = &arena[b ? OFF_X1 : OFF_X0];
#pragma unroll
      for (int kt = 0; kt < 2; ++kt) {
        bf16x8 af = *(const bf16x8*)&aggS[fm * AGG_STRIDE_S + fg * 8 + kt * 32];
        union { bf16x8 v; unsigned u[4]; } bu;
#pragma unroll
        for (int p = 0; p < 4; ++p) {
          float x0 = Xb[(kt * 32 + fg * 8 + 2 * p    ) * CH + ch0 + fm];
          float x1 = Xb[(kt * 32 + fg * 8 + 2 * p + 1) * CH + ch0 + fm];
          bu.u[p] = f2bfu(x0) | (f2bfu(x1) << 16);
        }
        acc = __builtin_amdgcn_mfma_f32_16x16x32_bf16(af, bu.v, acc, 0, 0, 0);
      }
    }
  }

  // ---- finalize: H (16x64, distributed per m89 D-layout) -> LDS -> linear
  __syncthreads();
  float* hT = arena;                       // reuse: [16][68]
#pragma unroll
  for (int r = 0; r < 4; ++r)
    hT[(fg * 4 + r) * HT_STRIDE + ch0 + fm] = acc[r];
  __syncthreads();

  const int c0 = cg * 4;
  float s0 = lb[c0 + 0] + bias[c0 + 0];
  float s1 = lb[c0 + 1] + bias[c0 + 1];
  float s2 = lb[c0 + 2] + bias[c0 + 2];
  float s3 = lb[c0 + 3] + bias[c0 + 3];
#pragma unroll
  for (int k4 = 0; k4 < CH / 4; ++k4) {
    float4 hv = *(const float4*)&hT[rg * HT_STRIDE + k4 * 4];
    float4 w0 = *(const float4*)&lw[(size_t)(c0 + 0) * CH + k4 * 4];
    float4 w1 = *(const float4*)&lw[(size_t)(c0 + 1) * CH + k4 * 4];
    float4 w2 = *(const float4*)&lw[(size_t)(c0 + 2) * CH + k4 * 4];
    float4 w3 = *(const float4*)&lw[(size_t)(c0 + 3) * CH + k4 * 4];
    s0 += hv.x * w0.x + hv.y * w0.y + hv.z * w0.z + hv.w * w0.w;
    s1 += hv.x * w1.x + hv.y * w1.y + hv.z * w1.z + hv.w * w1.w;
    s2 += hv.x * w2.x + hv.y * w2.y + hv.z * w2.z + hv.w * w2.w;
    s3 += hv.x * w3.x + hv.y * w3.y + hv.z * w3.z + hv.w * w3.w;
  }
  *(float4*)&out[(size_t)(n0 + rg) * CH + c0] = make_float4(s0, s1, s2, s3);
}

extern "C" void kernel_launch(void* const* d_in, const int* in_sizes, int n_in,
                              void* d_out, int out_size, void* d_ws, size_t ws_size,
                              hipStream_t stream) {
  const float* A    = (const float*)d_in[0];
  const float* X    = (const float*)d_in[1];
  const float* Wt   = (const float*)d_in[2];
  const float* lw   = (const float*)d_in[3];
  const float* lb   = (const float*)d_in[4];
  const float* bias = (const float*)d_in[5];
  float* out = (float*)d_out;

  gtn_fused<<<dim3(NBLK), 256, 0, stream>>>(A, X, Wt, lw, lb, bias, out);
}

// Round 4
// 199.786 us; speedup vs baseline: 6.4783x; 1.3197x over previous
//
#include <hip/hip_runtime.h>
#include <math.h>

// FastGTNLayer fused: out = (sum_e scale[e]*A[e]) @ X @ lin_w^T + lin_b + bias
// A: [4][8192][8192] f32, streamed once via global_load_lds DMA (HBM floor ~165us).
// GEMM on matrix pipe (mfma_f32_16x16x32_bf16); X pre-packed to B-fragment bf16
// layout in d_ws so the per-tile B operand is one conflict-free ds_read_b128.

#define NN 8192
#define CH 64
#define RB 16                 // rows per block
#define KT 64                 // k-tile
#define NT (NN / KT)          // 128 tiles
#define NBLK (NN / RB)        // 512 blocks

#define A_BUF_F 4096          // 4e * 16r * 64k floats
#define OFF_A0 0
#define OFF_A1 (A_BUF_F)
#define OFF_X0 (2 * A_BUF_F)
#define AGG_STRIDE_S 72       // shorts per agg row (144 B, 16B-aligned, bank-spread)
#define AGG_F ((RB * AGG_STRIDE_S) / 2)
#define HT_STRIDE 68
#define XPACK_UINTS_PER_TILE 2048   // 4wv * 2kt * 64lane * 4uint = 8 KB

typedef __attribute__((ext_vector_type(8))) short bf16x8;
typedef __attribute__((ext_vector_type(4))) float f32x4;

__device__ __forceinline__ void dma16(const float* g, float* l) {
  __builtin_amdgcn_global_load_lds(
      (const __attribute__((address_space(1))) void*)g,
      (__attribute__((address_space(3))) void*)l, 16, 0, 0);
}

__device__ __forceinline__ unsigned f2bfu(float f) {   // fp32 -> bf16 bits, RNE
  unsigned u = __float_as_uint(f);
  return (u + 0x7FFFu + ((u >> 16) & 1u)) >> 16;
}

// X -> bf16 B-fragment layout: ws[t][wv][kt][lane] = uint4, u[p] holds k-pair
// (bk+2p, bk+2p+1) at channel wv*16+fm, bk = t*64 + kt*32 + fg*8.
__global__ __launch_bounds__(256)
void gtn_packX(const float* __restrict__ X, unsigned* __restrict__ ws) {
  const int F = blockIdx.x * 256 + threadIdx.x;     // 0..65535
  const int t = F >> 9, rem = F & 511;
  const int wv = rem >> 7, kt = (rem >> 6) & 1, lane = rem & 63;
  const int fm = lane & 15, fg = lane >> 4;
  const int c = wv * 16 + fm;
  const int bk = t * KT + kt * 32 + fg * 8;
  uint4 o;
  o.x = f2bfu(X[(size_t)(bk + 0) * CH + c]) | (f2bfu(X[(size_t)(bk + 1) * CH + c]) << 16);
  o.y = f2bfu(X[(size_t)(bk + 2) * CH + c]) | (f2bfu(X[(size_t)(bk + 3) * CH + c]) << 16);
  o.z = f2bfu(X[(size_t)(bk + 4) * CH + c]) | (f2bfu(X[(size_t)(bk + 5) * CH + c]) << 16);
  o.w = f2bfu(X[(size_t)(bk + 6) * CH + c]) | (f2bfu(X[(size_t)(bk + 7) * CH + c]) << 16);
  *(uint4*)&ws[(size_t)F * 4] = o;
}

template<bool PACKED>
__global__ __launch_bounds__(256)
void gtn_fused(const float* __restrict__ A, const float* __restrict__ X,
               const unsigned* __restrict__ Xp,
               const float* __restrict__ Wt, const float* __restrict__ lw,
               const float* __restrict__ lb, const float* __restrict__ bias,
               float* __restrict__ out) {
  constexpr int XBUF_F   = PACKED ? 2048 : 4096;
  constexpr int OFF_X1   = OFF_X0 + XBUF_F;
  constexpr int OFF_AGG  = OFF_X0 + 2 * XBUF_F;
  constexpr int LDS_FLOATS = OFF_AGG + AGG_F;      // packed: 12864 f = 50.3 KB
  __shared__ __align__(16) float arena[LDS_FLOATS];

  const int tid = threadIdx.x;
  const int n0  = blockIdx.x * RB;

  // scale[e] = sum_c softmax(weight, axis=0)[e,c]
  float sc0, sc1, sc2, sc3;
  {
    float a0 = Wt[0], a1 = Wt[2], a2 = Wt[4], a3 = Wt[6];
    float b0 = Wt[1], b1 = Wt[3], b2 = Wt[5], b3 = Wt[7];
    float ma = fmaxf(fmaxf(a0, a1), fmaxf(a2, a3));
    float mb = fmaxf(fmaxf(b0, b1), fmaxf(b2, b3));
    float ea0 = expf(a0 - ma), ea1 = expf(a1 - ma), ea2 = expf(a2 - ma), ea3 = expf(a3 - ma);
    float eb0 = expf(b0 - mb), eb1 = expf(b1 - mb), eb2 = expf(b2 - mb), eb3 = expf(b3 - mb);
    float ra = 1.f / (ea0 + ea1 + ea2 + ea3);
    float rb = 1.f / (eb0 + eb1 + eb2 + eb3);
    sc0 = ea0 * ra + eb0 * rb;  sc1 = ea1 * ra + eb1 * rb;
    sc2 = ea2 * ra + eb2 * rb;  sc3 = ea3 * ra + eb3 * rb;
  }

  // ---- DMA source bases (k=0), 16 B granules, LDS-linear in wave order
  const float* gA[4];
#pragma unroll
  for (int i = 0; i < 4; ++i) {
    const int s = tid + i * 256;
    const int e = s >> 8, r = (s >> 4) & 15, kq = s & 15;   // A: [e][r][kq*4]
    gA[i] = A + ((size_t)e << 26) + (size_t)(n0 + r) * NN + kq * 4;
  }
  const float* gX[4];        // fallback: raw f32 X tile
  const unsigned* gXp[2];    // packed: bf16 fragments
  if (PACKED) {
#pragma unroll
    for (int i = 0; i < 2; ++i) gXp[i] = Xp + (size_t)(tid + i * 256) * 4;
  } else {
#pragma unroll
    for (int i = 0; i < 4; ++i) {
      const int s = tid + i * 256;
      const int kk = s >> 4, cq = s & 15;                   // X: [kk][cq*4]
      gX[i] = X + (size_t)kk * CH + cq * 4;
    }
  }

  const int rg = tid >> 4, cg = tid & 15;       // combine / finalize map
  const int lane = tid & 63, wv = tid >> 6;     // mfma map
  const int ch0 = wv * 16;
  const int fm = lane & 15, fg = lane >> 4;

  // ---- prologue: DMA tile 0 into buffer 0
#pragma unroll
  for (int i = 0; i < 4; ++i) dma16(gA[i], &arena[OFF_A0 + (tid + i * 256) * 4]);
  if (PACKED) {
#pragma unroll
    for (int i = 0; i < 2; ++i)
      dma16((const float*)gXp[i], &arena[OFF_X0 + (tid + i * 256) * 4]);
  } else {
#pragma unroll
    for (int i = 0; i < 4; ++i) dma16(gX[i], &arena[OFF_X0 + (tid + i * 256) * 4]);
  }

  f32x4 acc = {0.f, 0.f, 0.f, 0.f};

  for (int t = 0; t < NT; ++t) {
    const int b = t & 1;

    // #A: tile-t DMA landed; all waves done with mfma(t-1) -> buf b^1 free
    asm volatile("s_waitcnt vmcnt(0)\n\ts_barrier" ::: "memory");

    if (t + 1 < NT) {
      float* Ad = &arena[b ? OFF_A0 : OFF_A1];
      float* Xd = &arena[b ? OFF_X0 : OFF_X1];
      const size_t koff = (size_t)(t + 1) * KT;
#pragma unroll
      for (int i = 0; i < 4; ++i) dma16(gA[i] + koff, Ad + (tid + i * 256) * 4);
      if (PACKED) {
        const size_t xoff = (size_t)(t + 1) * XPACK_UINTS_PER_TILE;
#pragma unroll
        for (int i = 0; i < 2; ++i)
          dma16((const float*)(gXp[i] + xoff), Xd + (tid + i * 256) * 4);
      } else {
#pragma unroll
        for (int i = 0; i < 4; ++i)
          dma16(gX[i] + koff * CH, Xd + (tid + i * 256) * 4);
      }
    }

    // ---- combine: agg[r][k] = sum_e sc[e]*A_e[r][k] -> bf16, m-major [16][72s]
    {
      const float* Ab = &arena[b ? OFF_A1 : OFF_A0];
      short* aggW = (short*)&arena[OFF_AGG];
      float gx = 0.f, gy = 0.f, gz = 0.f, gw = 0.f;
#pragma unroll
      for (int e = 0; e < 4; ++e) {
        const float s = (e == 0) ? sc0 : (e == 1) ? sc1 : (e == 2) ? sc2 : sc3;
        float4 v = *(const float4*)&Ab[(e * RB + rg) * KT + cg * 4];
        gx = fmaf(s, v.x, gx); gy = fmaf(s, v.y, gy);
        gz = fmaf(s, v.z, gz); gw = fmaf(s, v.w, gw);
      }
      unsigned u0 = f2bfu(gx) | (f2bfu(gy) << 16);
      unsigned u1 = f2bfu(gz) | (f2bfu(gw) << 16);
      *(uint2*)&aggW[rg * AGG_STRIDE_S + cg * 4] = make_uint2(u0, u1);
    }

    // #B: agg visible to all waves
    asm volatile("s_waitcnt lgkmcnt(0)\n\ts_barrier" ::: "memory");

    // ---- mfma: wave wv owns rows 0..15 x ch [ch0, ch0+16); 2 x 16x16x32
    {
      const short* aggS = (const short*)&arena[OFF_AGG];
#pragma unroll
      for (int kt = 0; kt < 2; ++kt) {
        bf16x8 af = *(const bf16x8*)&aggS[fm * AGG_STRIDE_S + fg * 8 + kt * 32];
        if (PACKED) {
          const unsigned* XbU = (const unsigned*)&arena[b ? OFF_X1 : OFF_X0];
          union { uint4 q; bf16x8 v; } xu;
          xu.q = *(const uint4*)&XbU[(((wv << 1) | kt) * 64 + lane) * 4];
          acc = __builtin_amdgcn_mfma_f32_16x16x32_bf16(af, xu.v, acc, 0, 0, 0);
        } else {
          const float* Xb = &arena[b ? OFF_X1 : OFF_X0];
          union { bf16x8 v; unsigned u[4]; } bu;
#pragma unroll
          for (int p = 0; p < 4; ++p) {
            float x0 = Xb[(kt * 32 + fg * 8 + 2 * p    ) * CH + ch0 + fm];
            float x1 = Xb[(kt * 32 + fg * 8 + 2 * p + 1) * CH + ch0 + fm];
            bu.u[p] = f2bfu(x0) | (f2bfu(x1) << 16);
          }
          acc = __builtin_amdgcn_mfma_f32_16x16x32_bf16(af, bu.v, acc, 0, 0, 0);
        }
      }
    }
  }

  // ---- finalize: H (16x64, m89 D-layout) -> LDS -> row-linear linear layer
  __syncthreads();
  float* hT = arena;                       // reuse: [16][68]
#pragma unroll
  for (int r = 0; r < 4; ++r)
    hT[(fg * 4 + r) * HT_STRIDE + ch0 + fm] = acc[r];
  __syncthreads();

  const int c0 = cg * 4;
  float s0 = lb[c0 + 0] + bias[c0 + 0];
  float s1 = lb[c0 + 1] + bias[c0 + 1];
  float s2 = lb[c0 + 2] + bias[c0 + 2];
  float s3 = lb[c0 + 3] + bias[c0 + 3];
#pragma unroll
  for (int k4 = 0; k4 < CH / 4; ++k4) {
    float4 hv = *(const float4*)&hT[rg * HT_STRIDE + k4 * 4];
    float4 w0 = *(const float4*)&lw[(size_t)(c0 + 0) * CH + k4 * 4];
    float4 w1 = *(const float4*)&lw[(size_t)(c0 + 1) * CH + k4 * 4];
    float4 w2 = *(const float4*)&lw[(size_t)(c0 + 2) * CH + k4 * 4];
    float4 w3 = *(const float4*)&lw[(size_t)(c0 + 3) * CH + k4 * 4];
    s0 += hv.x * w0.x + hv.y * w0.y + hv.z * w0.z + hv.w * w0.w;
    s1 += hv.x * w1.x + hv.y * w1.y + hv.z * w1.z + hv.w * w1.w;
    s2 += hv.x * w2.x + hv.y * w2.y + hv.z * w2.z + hv.w * w2.w;
    s3 += hv.x * w3.x + hv.y * w3.y + hv.z * w3.z + hv.w * w3.w;
  }
  *(float4*)&out[(size_t)(n0 + rg) * CH + c0] = make_float4(s0, s1, s2, s3);
}

extern "C" void kernel_launch(void* const* d_in, const int* in_sizes, int n_in,
                              void* d_out, int out_size, void* d_ws, size_t ws_size,
                              hipStream_t stream) {
  const float* A    = (const float*)d_in[0];
  const float* X    = (const float*)d_in[1];
  const float* Wt   = (const float*)d_in[2];
  const float* lw   = (const float*)d_in[3];
  const float* lb   = (const float*)d_in[4];
  const float* bias = (const float*)d_in[5];
  float* out = (float*)d_out;

  const size_t packBytes = (size_t)NT * XPACK_UINTS_PER_TILE * 4;   // 1 MB
  if (ws_size >= packBytes) {
    gtn_packX<<<dim3(256), 256, 0, stream>>>(X, (unsigned*)d_ws);
    gtn_fused<true><<<dim3(NBLK), 256, 0, stream>>>(
        A, X, (const unsigned*)d_ws, Wt, lw, lb, bias, out);
  } else {
    gtn_fused<false><<<dim3(NBLK), 256, 0, stream>>>(
        A, X, nullptr, Wt, lw, lb, bias, out);
  }
}

// Round 5
// 197.999 us; speedup vs baseline: 6.5368x; 1.0090x over previous
//
#include <hip/hip_runtime.h>
#include <math.h>

// FastGTNLayer fused: out = (sum_e scale[e]*A[e]) @ X @ lin_w^T + lin_b + bias
// A: [4][8192][8192] f32, streamed once via global_load_lds DMA (HBM floor ~163us
// at measured 6.6 TB/s fill ceiling). GEMM on matrix pipe (mfma_f32_16x16x32_bf16),
// X pre-packed to B-fragment bf16 layout in d_ws.
// This round: 2-tile-deep prefetch, triple-buffered LDS, counted vmcnt (T3/T4) --
// the HBM queue never drains in the steady loop.

#define NN 8192
#define CH 64
#define RB 16                 // rows per block
#define KT 64                 // k-tile
#define NT (NN / KT)          // 128 tiles
#define NBLK (NN / RB)        // 512 blocks

#define A_BUF_F 4096          // 4e * 16r * 64k floats per A buffer
#define AGG_STRIDE_S 72       // shorts per agg row (144 B: 16B-aligned, bank-spread)
#define AGG_F ((RB * AGG_STRIDE_S) / 2)
#define HT_STRIDE 68
#define XPACK_UINTS_PER_TILE 2048   // 4wv * 2kt * 64lane * uint4 = 8 KB

typedef __attribute__((ext_vector_type(8))) short bf16x8;
typedef __attribute__((ext_vector_type(4))) float f32x4;

__device__ __forceinline__ void dma16(const float* g, float* l) {
  __builtin_amdgcn_global_load_lds(
      (const __attribute__((address_space(1))) void*)g,
      (__attribute__((address_space(3))) void*)l, 16, 0, 0);
}

__device__ __forceinline__ unsigned f2bfu(float f) {   // fp32 -> bf16 bits, RNE
  unsigned u = __float_as_uint(f);
  return (u + 0x7FFFu + ((u >> 16) & 1u)) >> 16;
}

// X -> bf16 B-fragment layout: ws[t][wv][kt][lane] = uint4; u[p] holds k-pair
// (bk+2p, bk+2p+1) at channel wv*16+fm, bk = t*64 + kt*32 + fg*8.
__global__ __launch_bounds__(256)
void gtn_packX(const float* __restrict__ X, unsigned* __restrict__ ws) {
  const int F = blockIdx.x * 256 + threadIdx.x;     // 0..65535
  const int t = F >> 9, rem = F & 511;
  const int wv = rem >> 7, kt = (rem >> 6) & 1, lane = rem & 63;
  const int fm = lane & 15, fg = lane >> 4;
  const int c = wv * 16 + fm;
  const int bk = t * KT + kt * 32 + fg * 8;
  uint4 o;
  o.x = f2bfu(X[(size_t)(bk + 0) * CH + c]) | (f2bfu(X[(size_t)(bk + 1) * CH + c]) << 16);
  o.y = f2bfu(X[(size_t)(bk + 2) * CH + c]) | (f2bfu(X[(size_t)(bk + 3) * CH + c]) << 16);
  o.z = f2bfu(X[(size_t)(bk + 4) * CH + c]) | (f2bfu(X[(size_t)(bk + 5) * CH + c]) << 16);
  o.w = f2bfu(X[(size_t)(bk + 6) * CH + c]) | (f2bfu(X[(size_t)(bk + 7) * CH + c]) << 16);
  *(uint4*)&ws[(size_t)F * 4] = o;
}

template<bool PACKED>
__global__ __launch_bounds__(256)
void gtn_fused(const float* __restrict__ A, const float* __restrict__ X,
               const unsigned* __restrict__ Xp,
               const float* __restrict__ Wt, const float* __restrict__ lw,
               const float* __restrict__ lb, const float* __restrict__ bias,
               float* __restrict__ out) {
  constexpr int XBUF_F = PACKED ? 2048 : 4096;
  constexpr int OFF_X  = 3 * A_BUF_F;
  constexpr int OFF_AGG = OFF_X + 3 * XBUF_F;
  constexpr int LDS_FLOATS = OFF_AGG + AGG_F;   // packed: 19008 f = 76 KB -> 2 blk/CU
  __shared__ __align__(16) float arena[LDS_FLOATS];

  const int tid = threadIdx.x;
  const int n0  = blockIdx.x * RB;

  // scale[e] = sum_c softmax(weight, axis=0)[e,c]
  float sc0, sc1, sc2, sc3;
  {
    float a0 = Wt[0], a1 = Wt[2], a2 = Wt[4], a3 = Wt[6];
    float b0 = Wt[1], b1 = Wt[3], b2 = Wt[5], b3 = Wt[7];
    float ma = fmaxf(fmaxf(a0, a1), fmaxf(a2, a3));
    float mb = fmaxf(fmaxf(b0, b1), fmaxf(b2, b3));
    float ea0 = expf(a0 - ma), ea1 = expf(a1 - ma), ea2 = expf(a2 - ma), ea3 = expf(a3 - ma);
    float eb0 = expf(b0 - mb), eb1 = expf(b1 - mb), eb2 = expf(b2 - mb), eb3 = expf(b3 - mb);
    float ra = 1.f / (ea0 + ea1 + ea2 + ea3);
    float rb = 1.f / (eb0 + eb1 + eb2 + eb3);
    sc0 = ea0 * ra + eb0 * rb;  sc1 = ea1 * ra + eb1 * rb;
    sc2 = ea2 * ra + eb2 * rb;  sc3 = ea3 * ra + eb3 * rb;
  }

  // ---- DMA source bases (k=0), 16 B granules, LDS-linear in wave order
  const float* gA[4];
#pragma unroll
  for (int i = 0; i < 4; ++i) {
    const int s = tid + i * 256;
    const int e = s >> 8, r = (s >> 4) & 15, kq = s & 15;   // A: [e][r][kq*4]
    gA[i] = A + ((size_t)e << 26) + (size_t)(n0 + r) * NN + kq * 4;
  }
  const unsigned* gXp[2];
  const float* gX[4];
  if constexpr (PACKED) {
#pragma unroll
    for (int i = 0; i < 2; ++i) gXp[i] = Xp + (size_t)(tid + i * 256) * 4;
  } else {
#pragma unroll
    for (int i = 0; i < 4; ++i) {
      const int s = tid + i * 256;
      const int kk = s >> 4, cq = s & 15;                   // X: [kk][cq*4]
      gX[i] = X + (size_t)kk * CH + cq * 4;
    }
  }

  const int rg = tid >> 4, cg = tid & 15;       // combine / finalize map
  const int lane = tid & 63, wv = tid >> 6;     // mfma map
  const int ch0 = wv * 16;
  const int fm = lane & 15, fg = lane >> 4;

  // ---- issue slot: tile u into A-buf / X-buf index bi
  auto issueS = [&](int u, int bi) {
    const size_t koff = (size_t)u * KT;
    float* Ad = &arena[bi * A_BUF_F];
    float* Xd = &arena[OFF_X + bi * XBUF_F];
#pragma unroll
    for (int i = 0; i < 4; ++i) dma16(gA[i] + koff, Ad + (tid + i * 256) * 4);
    if constexpr (PACKED) {
      const size_t xoff = (size_t)u * XPACK_UINTS_PER_TILE;
#pragma unroll
      for (int i = 0; i < 2; ++i)
        dma16((const float*)(gXp[i] + xoff), Xd + (tid + i * 256) * 4);
    } else {
#pragma unroll
      for (int i = 0; i < 4; ++i)
        dma16(gX[i] + koff * CH, Xd + (tid + i * 256) * 4);
    }
  };

  // ---- combine: agg[r][k] = sum_e sc[e]*A_e[r][k] -> bf16, m-major [16][72s]
  auto combine = [&](int bi) {
    const float* Ab = &arena[bi * A_BUF_F];
    short* aggW = (short*)&arena[OFF_AGG];
    float gx = 0.f, gy = 0.f, gz = 0.f, gw = 0.f;
#pragma unroll
    for (int e = 0; e < 4; ++e) {
      const float s = (e == 0) ? sc0 : (e == 1) ? sc1 : (e == 2) ? sc2 : sc3;
      float4 v = *(const float4*)&Ab[(e * RB + rg) * KT + cg * 4];
      gx = fmaf(s, v.x, gx); gy = fmaf(s, v.y, gy);
      gz = fmaf(s, v.z, gz); gw = fmaf(s, v.w, gw);
    }
    unsigned u0 = f2bfu(gx) | (f2bfu(gy) << 16);
    unsigned u1 = f2bfu(gz) | (f2bfu(gw) << 16);
    *(uint2*)&aggW[rg * AGG_STRIDE_S + cg * 4] = make_uint2(u0, u1);
  };

  f32x4 acc = {0.f, 0.f, 0.f, 0.f};

  // ---- mfma: wave wv owns rows 0..15 x ch [ch0, ch0+16); 2 x 16x16x32
  auto domfma = [&](int bi) {
    const short* aggS = (const short*)&arena[OFF_AGG];
#pragma unroll
    for (int kt = 0; kt < 2; ++kt) {
      bf16x8 af = *(const bf16x8*)&aggS[fm * AGG_STRIDE_S + fg * 8 + kt * 32];
      if constexpr (PACKED) {
        const unsigned* XbU = (const unsigned*)&arena[OFF_X + bi * XBUF_F];
        union { uint4 q; bf16x8 v; } xu;
        xu.q = *(const uint4*)&XbU[(((wv << 1) | kt) * 64 + lane) * 4];
        acc = __builtin_amdgcn_mfma_f32_16x16x32_bf16(af, xu.v, acc, 0, 0, 0);
      } else {
        const float* Xb = &arena[OFF_X + bi * XBUF_F];
        union { bf16x8 v; unsigned u[4]; } bu;
#pragma unroll
        for (int p = 0; p < 4; ++p) {
          float x0 = Xb[(kt * 32 + fg * 8 + 2 * p    ) * CH + ch0 + fm];
          float x1 = Xb[(kt * 32 + fg * 8 + 2 * p + 1) * CH + ch0 + fm];
          bu.u[p] = f2bfu(x0) | (f2bfu(x1) << 16);
        }
        acc = __builtin_amdgcn_mfma_f32_16x16x32_bf16(af, bu.v, acc, 0, 0, 0);
      }
    }
  };

  // ---- prologue: S(0), S(1) in flight (12 vm ops/thread packed, 16 raw)
  issueS(0, 0);
  issueS(1, 1);

  // ---- steady loop, t = 0..NT-3: 2-deep prefetch, counted waits, no drains.
  // Per-thread vm stream per slot: A x4 then X x2 (packed) / x4 (raw).
  // W1 (A(t) landed): newer = X(t) + S(t+1)          = 8  (12 raw)
  // W2 (X(t) landed): newer = S(t+1) + S(t+2)        = 12 (16 raw)
  int bi = 0;                                    // t % 3
  for (int t = 0; t < NT - 2; ++t) {
    int b2 = bi + 2; if (b2 >= 3) b2 -= 3;
    if constexpr (PACKED)
      asm volatile("s_waitcnt vmcnt(8)\n\ts_barrier" ::: "memory");
    else
      asm volatile("s_waitcnt vmcnt(12)\n\ts_barrier" ::: "memory");
    issueS(t + 2, b2);
    combine(bi);
    asm volatile("s_waitcnt lgkmcnt(0)\n\ts_barrier" ::: "memory");
    if constexpr (PACKED)
      asm volatile("s_waitcnt vmcnt(12)" ::: "memory");
    else
      asm volatile("s_waitcnt vmcnt(16)" ::: "memory");
    domfma(bi);
    ++bi; if (bi == 3) bi = 0;
  }

  // ---- peel t = NT-2 (bi wrapped to 0): nothing new to issue
  {
    if constexpr (PACKED)
      asm volatile("s_waitcnt vmcnt(8)\n\ts_barrier" ::: "memory");
    else
      asm volatile("s_waitcnt vmcnt(12)\n\ts_barrier" ::: "memory");
    combine(bi);
    asm volatile("s_waitcnt lgkmcnt(0)\n\ts_barrier" ::: "memory");
    if constexpr (PACKED)
      asm volatile("s_waitcnt vmcnt(6)" ::: "memory");
    else
      asm volatile("s_waitcnt vmcnt(8)" ::: "memory");
    domfma(bi);
    ++bi; if (bi == 3) bi = 0;
  }
  // ---- peel t = NT-1
  {
    if constexpr (PACKED)
      asm volatile("s_waitcnt vmcnt(2)\n\ts_barrier" ::: "memory");
    else
      asm volatile("s_waitcnt vmcnt(4)\n\ts_barrier" ::: "memory");
    combine(bi);
    asm volatile("s_waitcnt lgkmcnt(0)\n\ts_barrier" ::: "memory");
    asm volatile("s_waitcnt vmcnt(0)" ::: "memory");
    domfma(bi);
  }

  // ---- finalize: H (16x64, m89 D-layout) -> LDS -> row-linear linear layer
  __syncthreads();
  float* hT = arena;                       // reuse: [16][68]
#pragma unroll
  for (int r = 0; r < 4; ++r)
    hT[(fg * 4 + r) * HT_STRIDE + ch0 + fm] = acc[r];
  __syncthreads();

  const int c0 = cg * 4;
  float s0 = lb[c0 + 0] + bias[c0 + 0];
  float s1 = lb[c0 + 1] + bias[c0 + 1];
  float s2 = lb[c0 + 2] + bias[c0 + 2];
  float s3 = lb[c0 + 3] + bias[c0 + 3];
#pragma unroll
  for (int k4 = 0; k4 < CH / 4; ++k4) {
    float4 hv = *(const float4*)&hT[rg * HT_STRIDE + k4 * 4];
    float4 w0 = *(const float4*)&lw[(size_t)(c0 + 0) * CH + k4 * 4];
    float4 w1 = *(const float4*)&lw[(size_t)(c0 + 1) * CH + k4 * 4];
    float4 w2 = *(const float4*)&lw[(size_t)(c0 + 2) * CH + k4 * 4];
    float4 w3 = *(const float4*)&lw[(size_t)(c0 + 3) * CH + k4 * 4];
    s0 += hv.x * w0.x + hv.y * w0.y + hv.z * w0.z + hv.w * w0.w;
    s1 += hv.x * w1.x + hv.y * w1.y + hv.z * w1.z + hv.w * w1.w;
    s2 += hv.x * w2.x + hv.y * w2.y + hv.z * w2.z + hv.w * w2.w;
    s3 += hv.x * w3.x + hv.y * w3.y + hv.z * w3.z + hv.w * w3.w;
  }
  *(float4*)&out[(size_t)(n0 + rg) * CH + c0] = make_float4(s0, s1, s2, s3);
}

extern "C" void kernel_launch(void* const* d_in, const int* in_sizes, int n_in,
                              void* d_out, int out_size, void* d_ws, size_t ws_size,
                              hipStream_t stream) {
  const float* A    = (const float*)d_in[0];
  const float* X    = (const float*)d_in[1];
  const float* Wt   = (const float*)d_in[2];
  const float* lw   = (const float*)d_in[3];
  const float* lb   = (const float*)d_in[4];
  const float* bias = (const float*)d_in[5];
  float* out = (float*)d_out;

  const size_t packBytes = (size_t)NT * XPACK_UINTS_PER_TILE * 4;   // 1 MB
  if (ws_size >= packBytes) {
    gtn_packX<<<dim3(256), 256, 0, stream>>>(X, (unsigned*)d_ws);
    gtn_fused<true><<<dim3(NBLK), 256, 0, stream>>>(
        A, X, (const unsigned*)d_ws, Wt, lw, lb, bias, out);
  } else {
    gtn_fused<false><<<dim3(NBLK), 256, 0, stream>>>(
        A, X, nullptr, Wt, lw, lb, bias, out);
  }
}